// Round 2
// baseline (508.482 us; speedup 1.0000x reference)
//
#include <hip/hip_runtime.h>
#include <stdint.h>

#define B_TOK 8192
#define DIM   2048
#define NE    8
#define BM 128
#define BN 128
#define BK 64

typedef __bf16 bf16x8 __attribute__((ext_vector_type(8)));
typedef float  f32x4  __attribute__((ext_vector_type(4)));

__device__ __forceinline__ unsigned short f2b(float f) {
  unsigned u = __builtin_bit_cast(unsigned, f);
  u += 0x7fffu + ((u >> 16) & 1u);   // round-to-nearest-even
  return (unsigned short)(u >> 16);
}
__device__ __forceinline__ uint2 pack4(float4 v) {
  uint2 r;
  r.x = (unsigned)f2b(v.x) | ((unsigned)f2b(v.y) << 16);
  r.y = (unsigned)f2b(v.z) | ((unsigned)f2b(v.w) << 16);
  return r;
}
__device__ __forceinline__ void gload16(const void* g, void* l) {
  __builtin_amdgcn_global_load_lds(
      (const __attribute__((address_space(1))) void*)g,
      (__attribute__((address_space(3))) void*)l, 16, 0, 0);
}

// ---------------- f32 -> bf16 conversion passes ----------------------------
__global__ __launch_bounds__(256) void cvt_we(const float* __restrict__ src,
                                              unsigned short* __restrict__ dst) {
  size_t idx = (size_t)blockIdx.x * 256 + threadIdx.x;     // float4 index
  float4 v = *(const float4*)(src + idx * 4);
  *(uint2*)(dst + idx * 4) = pack4(v);
}

__global__ __launch_bounds__(256) void cvt_inp(const float* __restrict__ x,
                                               const float* __restrict__ y,
                                               unsigned short* __restrict__ dst) {
  size_t idx = (size_t)blockIdx.x * 256 + threadIdx.x;     // float4 index over [8192][512]
  int tok = (int)(idx >> 9);
  int c4  = (int)(idx & 511);
  const float* src = (c4 < 256) ? (x + (size_t)tok * 1024 + c4 * 4)
                                : (y + (size_t)tok * 1024 + (c4 - 256) * 4);
  float4 v = *(const float4*)src;
  *(uint2*)(dst + (size_t)tok * 2048 + c4 * 4) = pack4(v);
}

// ---------------- gating: one wave per token, exact f64 --------------------
__global__ void gate_kernel(const float* __restrict__ x,
                            const float* __restrict__ y,
                            const float* __restrict__ gW,
                            const float* __restrict__ gb,
                            int* __restrict__ counts,
                            int* __restrict__ perm) {
  const int tid = threadIdx.x;
  const int ln = tid & 63;
  const int token = blockIdx.x * 4 + (tid >> 6);

  double acc[NE];
#pragma unroll
  for (int e = 0; e < NE; ++e) acc[e] = 0.0;

  const float* bases[2] = {x, y};
#pragma unroll
  for (int p = 0; p < 2; ++p) {
    const float* rowp = bases[p] + (size_t)token * 1024;
#pragma unroll
    for (int it = 0; it < 4; ++it) {
      const int d = it * 256 + ln * 4;
      float4 v = *(const float4*)(rowp + d);
#pragma unroll
      for (int e = 0; e < NE; ++e) {
        float4 g = *(const float4*)(gW + e * DIM + p * 1024 + d);
        acc[e] += (double)v.x * (double)g.x + (double)v.y * (double)g.y +
                  (double)v.z * (double)g.z + (double)v.w * (double)g.w;
      }
    }
  }
#pragma unroll
  for (int e = 0; e < NE; ++e) {
#pragma unroll
    for (int off = 32; off >= 1; off >>= 1) acc[e] += __shfl_xor(acc[e], off, 64);
  }
  if (ln == 0) {
    int best = 0;
    double bv = acc[0] + (double)gb[0];
#pragma unroll
    for (int e = 1; e < NE; ++e) {
      double v = acc[e] + (double)gb[e];
      if (v > bv) { bv = v; best = e; }   // strict > keeps lowest index on ties
    }
    int pos = atomicAdd(&counts[best], 1);
    perm[best * B_TOK + pos] = token;
  }
}

// ---------------- grouped GEMM: out[tok] = We[e] @ inp[tok] + be[e] --------
template <bool PRE>
__global__ __launch_bounds__(256) void moe_gemm(
    const float* __restrict__ x,
    const float* __restrict__ y,
    const float* __restrict__ We,
    const float* __restrict__ be,
    const unsigned short* __restrict__ inpB,   // bf16 [8192][2048] (PRE only)
    const unsigned short* __restrict__ WeB,    // bf16 [8][2048][2048] (PRE only)
    const int* __restrict__ counts,
    const int* __restrict__ perm,
    float* __restrict__ out) {
  __shared__ unsigned short As[BM * BK];
  __shared__ unsigned short Bs[BN * BK];
  __shared__ int tokLds[BM];

  const int e = blockIdx.z;
  const int cnt = counts[e];
  const int m0 = blockIdx.y * BM;
  if (m0 >= cnt) return;
  const int n0 = blockIdx.x * BN;

  const int tid = threadIdx.x;
  const int ln = tid & 63;
  const int wv = tid >> 6;
  const int wm = wv & 1, wn = wv >> 1;

  if (tid < BM) {
    int r = m0 + tid;
    tokLds[tid] = perm[e * B_TOK + (r < cnt ? r : cnt - 1)];
  }
  __syncthreads();

  int tokA[4], rowB[4];
  const int c16 = ln & 7;
#pragma unroll
  for (int j = 0; j < 4; ++j) {
    int row = (wv * 4 + j) * 8 + (ln >> 3);   // 8 rows per issue, 16B/lane
    tokA[j] = tokLds[row];
    rowB[j] = row;
  }
  const unsigned short* wbbase = WeB + (size_t)e * DIM * DIM;
  const float* wfbase = We + (size_t)e * DIM * DIM;

  f32x4 acc[4][4];
#pragma unroll
  for (int i = 0; i < 4; ++i)
#pragma unroll
    for (int j = 0; j < 4; ++j) acc[i][j] = (f32x4){0.f, 0.f, 0.f, 0.f};

  for (int k0 = 0; k0 < DIM; k0 += BK) {
    __syncthreads();
    if constexpr (PRE) {
#pragma unroll
      for (int j = 0; j < 4; ++j) {
        gload16(inpB + (size_t)tokA[j] * DIM + k0 + c16 * 8,
                &As[(wv * 4 + j) * 512]);
        gload16(wbbase + (size_t)(n0 + rowB[j]) * DIM + k0 + c16 * 8,
                &Bs[(wv * 4 + j) * 512]);
      }
    } else {
      const float* ab = (k0 < 1024) ? x : y;
      const int kk = k0 & 1023;
#pragma unroll
      for (int i = 0; i < 8; ++i) {
        int li = i * 256 + tid;            // 2048 float4 per tile
        int row = li >> 4, k4 = li & 15;
        int tok = tokLds[row];
        float4 va = *(const float4*)(ab + (size_t)tok * 1024 + kk + k4 * 4);
        *(uint2*)&As[row * BK + k4 * 4] = pack4(va);
        float4 vb = *(const float4*)(wfbase + (size_t)(n0 + row) * DIM + k0 + k4 * 4);
        *(uint2*)&Bs[row * BK + k4 * 4] = pack4(vb);
      }
    }
    __syncthreads();

#pragma unroll
    for (int ks = 0; ks < 2; ++ks) {
      bf16x8 av[4], bv[4];
#pragma unroll
      for (int i = 0; i < 4; ++i)
        av[i] = *(const bf16x8*)&As[(wm * 64 + i * 16 + (ln & 15)) * BK + ks * 32 + (ln >> 4) * 8];
#pragma unroll
      for (int j = 0; j < 4; ++j)
        bv[j] = *(const bf16x8*)&Bs[(wn * 64 + j * 16 + (ln & 15)) * BK + ks * 32 + (ln >> 4) * 8];
#pragma unroll
      for (int i = 0; i < 4; ++i)
#pragma unroll
        for (int j = 0; j < 4; ++j)
          acc[i][j] = __builtin_amdgcn_mfma_f32_16x16x32_bf16(av[i], bv[j], acc[i][j], 0, 0, 0);
    }
  }

  // epilogue: += bias, scatter rows by token id, f32 store
  float bias[4]; int col[4];
#pragma unroll
  for (int j = 0; j < 4; ++j) {
    col[j] = n0 + wn * 64 + j * 16 + (ln & 15);
    bias[j] = be[e * DIM + col[j]];
  }
#pragma unroll
  for (int i = 0; i < 4; ++i) {
    int rbase = wm * 64 + i * 16 + ((ln >> 4) << 2);
#pragma unroll
    for (int r = 0; r < 4; ++r) {
      int rl = rbase + r;
      if (m0 + rl < cnt) {
        size_t t = (size_t)tokLds[rl];
#pragma unroll
        for (int j = 0; j < 4; ++j)
          out[t * DIM + col[j]] = acc[i][j][r] + bias[j];
      }
    }
  }
}

extern "C" void kernel_launch(void* const* d_in, const int* in_sizes, int n_in,
                              void* d_out, int out_size, void* d_ws, size_t ws_size,
                              hipStream_t stream) {
  const float* x  = (const float*)d_in[0];
  const float* y  = (const float*)d_in[1];
  const float* We = (const float*)d_in[2];
  const float* be = (const float*)d_in[3];
  const float* gW = (const float*)d_in[4];
  const float* gb = (const float*)d_in[5];
  float* out = (float*)d_out;

  char* ws = (char*)d_ws;
  int* counts = (int*)ws;                                   // @0, 8 ints
  int* perm   = (int*)(ws + 4096);                          // 8*8192 ints = 256 KiB
  unsigned short* inpB = (unsigned short*)(ws + 266240);    // 33.5 MB bf16 [8192][2048]
  unsigned short* WeB  = (unsigned short*)(ws + 33820672);  // 67.1 MB bf16 [8][2048][2048]
  const size_t needed = 33820672ull + 67108864ull;

  hipMemsetAsync(counts, 0, 8 * sizeof(int), stream);
  gate_kernel<<<dim3(B_TOK / 4), 256, 0, stream>>>(x, y, gW, gb, counts, perm);

  if (ws_size >= needed) {
    cvt_we<<<dim3(32768), 256, 0, stream>>>(We, WeB);
    cvt_inp<<<dim3(16384), 256, 0, stream>>>(x, y, inpB);
    moe_gemm<true><<<dim3(DIM / BN, B_TOK / BM, NE), 256, 0, stream>>>(
        x, y, We, be, inpB, WeB, counts, perm, out);
  } else {
    moe_gemm<false><<<dim3(DIM / BN, B_TOK / BM, NE), 256, 0, stream>>>(
        x, y, We, be, nullptr, nullptr, counts, perm, out);
  }
}

// Round 3
// 431.300 us; speedup vs baseline: 1.1790x; 1.1790x over previous
//
#include <hip/hip_runtime.h>
#include <stdint.h>

#define B_TOK 8192
#define DIM   2048
#define NE    8
#define BM 128
#define BN 128
#define BK 64

typedef __bf16 bf16x8 __attribute__((ext_vector_type(8)));
typedef float  f32x4  __attribute__((ext_vector_type(4)));

__device__ __forceinline__ unsigned short f2b(float f) {
  unsigned u = __builtin_bit_cast(unsigned, f);
  u += 0x7fffu + ((u >> 16) & 1u);   // round-to-nearest-even
  return (unsigned short)(u >> 16);
}
__device__ __forceinline__ uint2 pack4(float4 v) {
  uint2 r;
  r.x = (unsigned)f2b(v.x) | ((unsigned)f2b(v.y) << 16);
  r.y = (unsigned)f2b(v.z) | ((unsigned)f2b(v.w) << 16);
  return r;
}
__device__ __forceinline__ void gload16(const void* g, void* l) {
  __builtin_amdgcn_global_load_lds(
      (const __attribute__((address_space(1))) void*)g,
      (__attribute__((address_space(3))) void*)l, 16, 0, 0);
}

// ---------------- f32 -> bf16 conversion for We ----------------------------
__global__ __launch_bounds__(256) void cvt_we(const float* __restrict__ src,
                                              unsigned short* __restrict__ dst) {
  size_t idx = (size_t)blockIdx.x * 256 + threadIdx.x;     // float4 index
  float4 v = *(const float4*)(src + idx * 4);
  *(uint2*)(dst + idx * 4) = pack4(v);
}

// ---------------- gating: one wave per token, exact f64, NO atomics --------
// Also fuses the x,y -> bf16 concat conversion (we already read every elem).
template <bool WINP>
__global__ void gate_kernel(const float* __restrict__ x,
                            const float* __restrict__ y,
                            const float* __restrict__ gW,
                            const float* __restrict__ gb,
                            int* __restrict__ eid,
                            unsigned short* __restrict__ inpB) {
  const int tid = threadIdx.x;
  const int ln = tid & 63;
  const int token = blockIdx.x * 4 + (tid >> 6);

  double acc[NE];
#pragma unroll
  for (int e = 0; e < NE; ++e) acc[e] = 0.0;

  const float* bases[2] = {x, y};
#pragma unroll
  for (int p = 0; p < 2; ++p) {
    const float* rowp = bases[p] + (size_t)token * 1024;
#pragma unroll
    for (int it = 0; it < 4; ++it) {
      const int d = it * 256 + ln * 4;
      float4 v = *(const float4*)(rowp + d);
      if (WINP)
        *(uint2*)(inpB + (size_t)token * DIM + p * 1024 + d) = pack4(v);
#pragma unroll
      for (int e = 0; e < NE; ++e) {
        float4 g = *(const float4*)(gW + e * DIM + p * 1024 + d);
        acc[e] += (double)v.x * (double)g.x + (double)v.y * (double)g.y +
                  (double)v.z * (double)g.z + (double)v.w * (double)g.w;
      }
    }
  }
#pragma unroll
  for (int e = 0; e < NE; ++e) {
#pragma unroll
    for (int off = 32; off >= 1; off >>= 1) acc[e] += __shfl_xor(acc[e], off, 64);
  }
  if (ln == 0) {
    int best = 0;
    double bv = acc[0] + (double)gb[0];
#pragma unroll
    for (int e = 1; e < NE; ++e) {
      double v = acc[e] + (double)gb[e];
      if (v > bv) { bv = v; best = e; }   // strict > keeps lowest index on ties
    }
    eid[token] = best;
  }
}

// ---------------- bucketize: deterministic token->expert lists -------------
// One block per expert; ballot + LDS scan; perm sorted ascending by token.
__global__ __launch_bounds__(256) void bucketize(const int* __restrict__ eid,
                                                 int* __restrict__ counts,
                                                 int* __restrict__ perm) {
  const int e = blockIdx.x;
  const int tid = threadIdx.x, ln = tid & 63, wv = tid >> 6;
  __shared__ int wsum[4];
  __shared__ int basev;
  if (tid == 0) basev = 0;
  __syncthreads();
  for (int t0 = 0; t0 < B_TOK; t0 += 256) {
    int t = t0 + tid;
    bool m = (eid[t] == e);
    unsigned long long mk = __ballot(m);
    int pre = __popcll(mk & ((1ull << ln) - 1ull));
    if (ln == 0) wsum[wv] = __popcll(mk);
    __syncthreads();
    int off = basev;
    for (int w = 0; w < wv; ++w) off += wsum[w];
    if (m) perm[e * B_TOK + off + pre] = t;
    __syncthreads();
    if (tid == 0) basev += wsum[0] + wsum[1] + wsum[2] + wsum[3];
    __syncthreads();   // protect wsum/basev from next-iter writes
  }
  if (tid == 0) counts[e] = basev;
}

// ---------------- grouped GEMM: out[tok] = We[e] @ inp[tok] + be[e] --------
// LDS layout XOR-swizzled: slot (row, c) holds global 16B-chunk c ^ (row&7).
template <bool PRE>
__global__ __launch_bounds__(256) void moe_gemm(
    const float* __restrict__ x,
    const float* __restrict__ y,
    const float* __restrict__ We,
    const float* __restrict__ be,
    const unsigned short* __restrict__ inpB,   // bf16 [8192][2048] (PRE only)
    const unsigned short* __restrict__ WeB,    // bf16 [8][2048][2048] (PRE only)
    const int* __restrict__ counts,
    const int* __restrict__ perm,
    float* __restrict__ out) {
  __shared__ unsigned short As[BM * BK];
  __shared__ unsigned short Bs[BN * BK];
  __shared__ int tokLds[BM];

  const int e = blockIdx.z;
  const int cnt = counts[e];
  const int m0 = blockIdx.y * BM;
  if (m0 >= cnt) return;
  const int n0 = blockIdx.x * BN;

  const int tid = threadIdx.x;
  const int ln = tid & 63;
  const int wv = tid >> 6;
  const int wm = wv & 1, wn = wv >> 1;

  if (tid < BM) {
    int r = m0 + tid;
    tokLds[tid] = perm[e * B_TOK + (r < cnt ? r : cnt - 1)];
  }
  __syncthreads();

  // staging: lane ln lands at LDS slot (row = g*8 + (ln>>3), c_slot = ln&7);
  // it must fetch global chunk c_slot ^ (row&7) = (ln&7) ^ ((ln>>3)&7).
  const int cS = (ln & 7) ^ ((ln >> 3) & 7);
  int tokA[4], rowB[4];
#pragma unroll
  for (int j = 0; j < 4; ++j) {
    int row = (wv * 4 + j) * 8 + (ln >> 3);   // 8 rows per issue, 16B/lane
    tokA[j] = tokLds[row];
    rowB[j] = row;
  }
  const unsigned short* wbbase = WeB + (size_t)e * DIM * DIM;
  const float* wfbase = We + (size_t)e * DIM * DIM;

  f32x4 acc[4][4];
#pragma unroll
  for (int i = 0; i < 4; ++i)
#pragma unroll
    for (int j = 0; j < 4; ++j) acc[i][j] = (f32x4){0.f, 0.f, 0.f, 0.f};

  for (int k0 = 0; k0 < DIM; k0 += BK) {
    __syncthreads();
    if constexpr (PRE) {
#pragma unroll
      for (int j = 0; j < 4; ++j) {
        gload16(inpB + (size_t)tokA[j] * DIM + k0 + cS * 8,
                &As[(wv * 4 + j) * 512]);
        gload16(wbbase + (size_t)(n0 + rowB[j]) * DIM + k0 + cS * 8,
                &Bs[(wv * 4 + j) * 512]);
      }
    } else {
      const float* ab = (k0 < 1024) ? x : y;
      const int kk = k0 & 1023;
#pragma unroll
      for (int i = 0; i < 8; ++i) {
        int li = i * 256 + tid;            // 2048 float4 per tile
        int row = li >> 4, k4 = li & 15;
        int ksl = (k4 & 7) ^ (row & 7);    // swizzled slot for chunk k4... store chunk k4 at slot k4^(row&7)
        // chunk index == 16B == 8 shorts == 2 float4; handle via 8-short granularity:
        // k4 counts float4 (8B of bf16): pair two float4 per 16B chunk.
        int chunk = k4 >> 1, half = k4 & 1;
        int slot = (chunk ^ (row & 7)) * 2 + half;
        int tok = tokLds[row];
        float4 va = *(const float4*)(ab + (size_t)tok * 1024 + kk + k4 * 4);
        *(uint2*)&As[row * BK + slot * 4] = pack4(va);
        float4 vb = *(const float4*)(wfbase + (size_t)(n0 + row) * DIM + k0 + k4 * 4);
        *(uint2*)&Bs[row * BK + slot * 4] = pack4(vb);
        (void)ksl;
      }
    }
    __syncthreads();

#pragma unroll
    for (int ks = 0; ks < 2; ++ks) {
      bf16x8 av[4], bv[4];
#pragma unroll
      for (int i = 0; i < 4; ++i) {
        int rA = wm * 64 + i * 16 + (ln & 15);
        int c = ks * 4 + (ln >> 4);
        av[i] = *(const bf16x8*)&As[rA * BK + (c ^ (rA & 7)) * 8];
      }
#pragma unroll
      for (int j = 0; j < 4; ++j) {
        int rB = wn * 64 + j * 16 + (ln & 15);
        int c = ks * 4 + (ln >> 4);
        bv[j] = *(const bf16x8*)&Bs[rB * BK + (c ^ (rB & 7)) * 8];
      }
#pragma unroll
      for (int i = 0; i < 4; ++i)
#pragma unroll
        for (int j = 0; j < 4; ++j)
          acc[i][j] = __builtin_amdgcn_mfma_f32_16x16x32_bf16(av[i], bv[j], acc[i][j], 0, 0, 0);
    }
  }

  // epilogue: += bias, scatter rows by token id, f32 store
  float bias[4]; int col[4];
#pragma unroll
  for (int j = 0; j < 4; ++j) {
    col[j] = n0 + wn * 64 + j * 16 + (ln & 15);
    bias[j] = be[e * DIM + col[j]];
  }
#pragma unroll
  for (int i = 0; i < 4; ++i) {
    int rbase = wm * 64 + i * 16 + ((ln >> 4) << 2);
#pragma unroll
    for (int r = 0; r < 4; ++r) {
      int rl = rbase + r;
      if (m0 + rl < cnt) {
        size_t t = (size_t)tokLds[rl];
#pragma unroll
        for (int j = 0; j < 4; ++j)
          out[t * DIM + col[j]] = acc[i][j][r] + bias[j];
      }
    }
  }
}

extern "C" void kernel_launch(void* const* d_in, const int* in_sizes, int n_in,
                              void* d_out, int out_size, void* d_ws, size_t ws_size,
                              hipStream_t stream) {
  const float* x  = (const float*)d_in[0];
  const float* y  = (const float*)d_in[1];
  const float* We = (const float*)d_in[2];
  const float* be = (const float*)d_in[3];
  const float* gW = (const float*)d_in[4];
  const float* gb = (const float*)d_in[5];
  float* out = (float*)d_out;

  char* ws = (char*)d_ws;
  int* counts = (int*)ws;                                   // @0, 8 ints (256B pad)
  int* eid    = (int*)(ws + 256);                           // 8192 ints
  int* perm   = (int*)(ws + 33024);                         // 8*8192 ints
  unsigned short* inpB = (unsigned short*)(ws + 295168);    // 33.5 MB bf16 [8192][2048]
  unsigned short* WeB  = (unsigned short*)(ws + 33849600);  // 67.1 MB bf16 [8][2048][2048]
  const size_t needed = 33849600ull + 67108864ull;

  if (ws_size >= needed) {
    gate_kernel<true><<<dim3(B_TOK / 4), 256, 0, stream>>>(x, y, gW, gb, eid, inpB);
    cvt_we<<<dim3(32768), 256, 0, stream>>>(We, WeB);
    bucketize<<<dim3(NE), 256, 0, stream>>>(eid, counts, perm);
    moe_gemm<true><<<dim3(DIM / BN, B_TOK / BM, NE), 256, 0, stream>>>(
        x, y, We, be, inpB, WeB, counts, perm, out);
  } else {
    gate_kernel<false><<<dim3(B_TOK / 4), 256, 0, stream>>>(x, y, gW, gb, eid, nullptr);
    bucketize<<<dim3(NE), 256, 0, stream>>>(eid, counts, perm);
    moe_gemm<false><<<dim3(DIM / BN, B_TOK / BM, NE), 256, 0, stream>>>(
        x, y, We, be, nullptr, nullptr, counts, perm, out);
  }
}